// Round 2
// baseline (1999.671 us; speedup 1.0000x reference)
//
#include <hip/hip_runtime.h>

#define CIN   32
#define COUT  64
#define TT    8
#define HH    56
#define WW    56
#define KK    27
#define SP    (TT * HH * WW)   // 25088
#define NB    2
#define CHUNK 16               // Cout per thread
#define NCHUNK (COUT / CHUNK)  // 4 chunk-waves per block
#define POSB  64               // positions per block (one wave's worth)

// weight [Cout][Cin][K] -> [K][Cin][Cout]; a chunk-wave reads 16 contiguous
// wave-uniform floats per (k,c) -> scalar s_load, zero VALU cost.
__global__ __launch_bounds__(256) void transpose_w_kernel(const float* __restrict__ w,
                                                          float* __restrict__ wt) {
    int i = blockIdx.x * 256 + threadIdx.x;
    if (i < COUT * CIN * KK) {
        int co = i / (CIN * KK);
        int r  = i % (CIN * KK);
        int c  = r / KK;
        int k  = r % KK;
        wt[(k * CIN + c) * COUT + co] = w[i];
    }
}

template <bool TRANS>
__global__ __launch_bounds__(256) void dconv3d_kernel(const float* __restrict__ x,
                                                      const float* __restrict__ off,
                                                      const float* __restrict__ w,
                                                      const float* __restrict__ bias,
                                                      float* __restrict__ out) {
    // Block = 64 consecutive spatial positions x 4 Cout-chunks.
    // chunk is wave-uniform (threadIdx.x>>6) -> weight loads stay scalar.
    const int lane  = threadIdx.x & 63;
    const int chunk = threadIdx.x >> 6;
    const int co0   = chunk * CHUNK;

    const int s  = blockIdx.x * POSB + lane;   // 784*64 == NB*SP exactly
    const int n  = s / SP;
    const int sp = s % SP;
    const int to = sp / (HH * WW);
    const int hw = sp % (HH * WW);
    const int ho = hw / WW;
    const int wo = hw % WW;

    float acc[CHUNK];
#pragma unroll
    for (int i = 0; i < CHUNK; ++i) acc[i] = 0.f;

    const float* xn   = x + (size_t)n * CIN * SP;
    const float* offn = off + (size_t)n * (3 * KK) * SP + sp;

    for (int k = 0; k < KK; ++k) {
        const int kt  = k / 9;
        const int khh = (k / 3) % 3;
        const int kww = k % 3;

        // stride=1, pad=1, dil=1: base = out_coord - 1 + tap
        const float pt = (float)(to - 1 + kt)  + offn[(k * 3 + 0) * SP];
        const float ph = (float)(ho - 1 + khh) + offn[(k * 3 + 1) * SP];
        const float pw = (float)(wo - 1 + kww) + offn[(k * 3 + 2) * SP];

        const float ft = floorf(pt), fh = floorf(ph), fw = floorf(pw);
        const float lt = pt - ft, lh = ph - fh, lw = pw - fw;
        const int t0 = (int)ft, h0 = (int)fh, w0 = (int)fw;

        // Per-axis corner weights with validity folded in (invalid -> weight 0),
        // clamped indices (matches reference clip + valid-mask semantics).
        float awt[2], awh[2], aww[2];
        int   it[2], ih[2], iw[2];
        {
            const int t1 = t0 + 1;
            awt[0] = (t0 >= 0 && t0 < TT) ? (1.f - lt) : 0.f;
            awt[1] = (t1 >= 0 && t1 < TT) ? lt : 0.f;
            it[0]  = min(max(t0, 0), TT - 1);
            it[1]  = min(max(t1, 0), TT - 1);
        }
        {
            const int h1 = h0 + 1;
            awh[0] = (h0 >= 0 && h0 < HH) ? (1.f - lh) : 0.f;
            awh[1] = (h1 >= 0 && h1 < HH) ? lh : 0.f;
            ih[0]  = min(max(h0, 0), HH - 1);
            ih[1]  = min(max(h1, 0), HH - 1);
        }
        {
            const int w1 = w0 + 1;
            aww[0] = (w0 >= 0 && w0 < WW) ? (1.f - lw) : 0.f;
            aww[1] = (w1 >= 0 && w1 < WW) ? lw : 0.f;
            iw[0]  = min(max(w0, 0), WW - 1);
            iw[1]  = min(max(w1, 0), WW - 1);
        }

        int   a[8];
        float cw[8];
#pragma unroll
        for (int ci = 0; ci < 8; ++ci) {
            const int i0 = ci >> 2, i1 = (ci >> 1) & 1, i2 = ci & 1;
            a[ci]  = (it[i0] * HH + ih[i1]) * WW + iw[i2];
            cw[ci] = awt[i0] * awh[i1] * aww[i2];
        }

#pragma unroll 4
        for (int c = 0; c < CIN; ++c) {
            const float* xc = xn + c * SP;
            float v = 0.f;
#pragma unroll
            for (int ci = 0; ci < 8; ++ci) v = fmaf(cw[ci], xc[a[ci]], v);

            if (TRANS) {
                const float* wk = w + (k * CIN + c) * COUT + co0;  // wave-uniform
#pragma unroll
                for (int i = 0; i < CHUNK; ++i) acc[i] = fmaf(v, wk[i], acc[i]);
            } else {
#pragma unroll
                for (int i = 0; i < CHUNK; ++i)
                    acc[i] = fmaf(v, w[((co0 + i) * CIN + c) * KK + k], acc[i]);
            }
        }
    }

    float* on = out + (size_t)n * COUT * SP + (size_t)co0 * SP + sp;
#pragma unroll
    for (int i = 0; i < CHUNK; ++i) on[i * SP] = acc[i] + bias[co0 + i];
}

extern "C" void kernel_launch(void* const* d_in, const int* in_sizes, int n_in,
                              void* d_out, int out_size, void* d_ws, size_t ws_size,
                              hipStream_t stream) {
    const float* x    = (const float*)d_in[0];
    const float* off  = (const float*)d_in[1];
    const float* w    = (const float*)d_in[2];
    const float* bias = (const float*)d_in[3];
    float* out        = (float*)d_out;

    const int blocks = (NB * SP) / POSB;  // 784 blocks, 256 threads each

    const size_t wt_bytes = (size_t)COUT * CIN * KK * sizeof(float);  // ~221 KB
    if (ws_size >= wt_bytes) {
        float* wt = (float*)d_ws;
        transpose_w_kernel<<<(COUT * CIN * KK + 255) / 256, 256, 0, stream>>>(w, wt);
        dconv3d_kernel<true><<<blocks, 256, 0, stream>>>(x, off, wt, bias, out);
    } else {
        dconv3d_kernel<false><<<blocks, 256, 0, stream>>>(x, off, w, bias, out);
    }
}

// Round 3
// 519.624 us; speedup vs baseline: 3.8483x; 3.8483x over previous
//
#include <hip/hip_runtime.h>

#define CIN   32
#define COUT  64
#define TT    8
#define HH    56
#define WW    56
#define KK    27
#define SP    (TT * HH * WW)   // 25088
#define NB    2
#define POSB  64               // positions per block (one wave-width)
#define CHUNK 16               // Cout per chunk-wave
#define CPT   8                // channels gathered per thread = CIN*POSB/256

// weight [Cout][Cin][K] -> [K][Cin][Cout] so GEMM reads contiguous
// wave-uniform floats (scalar s_load).
__global__ __launch_bounds__(256) void transpose_w_kernel(const float* __restrict__ w,
                                                          float* __restrict__ wt) {
    int i = blockIdx.x * 256 + threadIdx.x;
    if (i < COUT * CIN * KK) {
        int co = i / (CIN * KK);
        int r  = i % (CIN * KK);
        int c  = r / KK;
        int k  = r % KK;
        wt[(k * CIN + c) * COUT + co] = w[i];
    }
}

__global__ __launch_bounds__(256, 3) void dconv3d_kernel(const float* __restrict__ x,
                                                         const float* __restrict__ off,
                                                         const float* __restrict__ wt,
                                                         const float* __restrict__ bias,
                                                         float* __restrict__ out) {
    // Double-buffered interpolated tile: vt[buf][c][pos]
    __shared__ float vt[2][CIN * POSB];

    const int lane  = threadIdx.x & 63;
    const int chunk = threadIdx.x >> 6;          // wave-uniform by construction
    // Force the compiler to see chunk-derived values as scalar (SGPR):
    const int co0 = __builtin_amdgcn_readfirstlane(chunk * CHUNK);

    const int s  = blockIdx.x * POSB + lane;     // 784*64 == NB*SP exactly
    const int n  = s / SP;
    const int sp = s % SP;
    const int to = sp / (HH * WW);
    const int hw = sp % (HH * WW);
    const int ho = hw / WW;
    const int wo = hw % WW;

    float acc[CHUNK];
#pragma unroll
    for (int i = 0; i < CHUNK; ++i) acc[i] = 0.f;

    const float* xn   = x + (size_t)n * CIN * SP;
    const float* offn = off + (size_t)n * (3 * KK) * SP + sp;

    // Prefetched offsets for the current tap
    float o0 = offn[0];
    float o1 = offn[SP];
    float o2 = offn[2 * SP];

    for (int k = 0; k < KK; ++k) {
        const int kt  = k / 9;
        const int khh = (k / 3) % 3;
        const int kww = k % 3;

        // stride=1, pad=1, dil=1: base = out_coord - 1 + tap
        const float pt = (float)(to - 1 + kt)  + o0;
        const float ph = (float)(ho - 1 + khh) + o1;
        const float pw = (float)(wo - 1 + kww) + o2;

        // Prefetch next tap's offsets early (hide L2 latency under interp+gemm)
        if (k + 1 < KK) {
            o0 = offn[((k + 1) * 3 + 0) * SP];
            o1 = offn[((k + 1) * 3 + 1) * SP];
            o2 = offn[((k + 1) * 3 + 2) * SP];
        }

        const float ft = floorf(pt), fh = floorf(ph), fw = floorf(pw);
        const float lt = pt - ft, lh = ph - fh, lw = pw - fw;
        const int t0 = (int)ft, h0 = (int)fh, w0 = (int)fw;

        // Per-axis corner weights with validity folded in (invalid -> 0),
        // clamped indices (matches reference clip + valid-mask semantics).
        float awt[2], awh[2], aww[2];
        int   it[2], ih[2], iw[2];
        {
            const int t1 = t0 + 1;
            awt[0] = (t0 >= 0 && t0 < TT) ? (1.f - lt) : 0.f;
            awt[1] = (t1 >= 0 && t1 < TT) ? lt : 0.f;
            it[0]  = min(max(t0, 0), TT - 1);
            it[1]  = min(max(t1, 0), TT - 1);
        }
        {
            const int h1 = h0 + 1;
            awh[0] = (h0 >= 0 && h0 < HH) ? (1.f - lh) : 0.f;
            awh[1] = (h1 >= 0 && h1 < HH) ? lh : 0.f;
            ih[0]  = min(max(h0, 0), HH - 1);
            ih[1]  = min(max(h1, 0), HH - 1);
        }
        {
            const int w1 = w0 + 1;
            aww[0] = (w0 >= 0 && w0 < WW) ? (1.f - lw) : 0.f;
            aww[1] = (w1 >= 0 && w1 < WW) ? lw : 0.f;
            iw[0]  = min(max(w0, 0), WW - 1);
            iw[1]  = min(max(w1, 0), WW - 1);
        }

        int   a[8];
        float cw[8];
#pragma unroll
        for (int ci = 0; ci < 8; ++ci) {
            const int i0 = ci >> 2, i1 = (ci >> 1) & 1, i2 = ci & 1;
            a[ci]  = (it[i0] * HH + ih[i1]) * WW + iw[i2];
            cw[ci] = awt[i0] * awh[i1] * aww[i2];
        }

        // ---- interp phase: this thread produces 8 channels for its position
        float* dst = &vt[k & 1][0];
#pragma unroll
        for (int j = 0; j < CPT; ++j) {
            const int c = j * 4 + chunk;
            const float* xc = xn + c * SP;
            float v = 0.f;
#pragma unroll
            for (int ci = 0; ci < 8; ++ci) v = fmaf(cw[ci], xc[a[ci]], v);
            dst[c * POSB + lane] = v;
        }

        __syncthreads();  // producers done; also orders gemm(k-1) before interp(k+1)

        // ---- GEMM phase: 16 Couts per thread, weights wave-uniform (scalar)
        const float* src = &vt[k & 1][0];
        const float* wk  = wt + (size_t)k * CIN * COUT + co0;
#pragma unroll
        for (int c = 0; c < CIN; ++c) {
            const float v = src[c * POSB + lane];
            const float* wkc = wk + c * COUT;
#pragma unroll
            for (int i = 0; i < CHUNK; ++i) acc[i] = fmaf(v, wkc[i], acc[i]);
        }
    }

    float* on = out + (size_t)n * COUT * SP + (size_t)co0 * SP + sp;
#pragma unroll
    for (int i = 0; i < CHUNK; ++i) on[i * SP] = acc[i] + bias[co0 + i];
}

extern "C" void kernel_launch(void* const* d_in, const int* in_sizes, int n_in,
                              void* d_out, int out_size, void* d_ws, size_t ws_size,
                              hipStream_t stream) {
    const float* x    = (const float*)d_in[0];
    const float* off  = (const float*)d_in[1];
    const float* w    = (const float*)d_in[2];
    const float* bias = (const float*)d_in[3];
    float* out        = (float*)d_out;

    const int blocks = (NB * SP) / POSB;  // 784 blocks of 256 threads

    float* wtp = (float*)d_ws;            // 221 KB transposed weight
    transpose_w_kernel<<<(COUT * CIN * KK + 255) / 256, 256, 0, stream>>>(w, wtp);
    dconv3d_kernel<<<blocks, 256, 0, stream>>>(x, off, wtp, bias, out);
}

// Round 4
// 191.314 us; speedup vs baseline: 10.4523x; 2.7161x over previous
//
#include <hip/hip_runtime.h>

#define CIN   32
#define COUT  64
#define TT    8
#define HH    56
#define WW    56
#define KK    27
#define SP    (TT * HH * WW)   // 25088
#define NB    2
#define POSB  64               // positions per block
#define CHUNK 16               // Cout per chunk-wave (gemm persona)
#define VSTR  66               // LDS leading stride for vt (2-way only on r/w)

// ---- weight [Cout][Cin][K] -> [K][Cin][Cout] (contiguous wave-uniform reads)
__global__ __launch_bounds__(256) void transpose_w_kernel(const float* __restrict__ w,
                                                          float* __restrict__ wt) {
    int i = blockIdx.x * 256 + threadIdx.x;
    if (i < COUT * CIN * KK) {
        int co = i / (CIN * KK);
        int r  = i % (CIN * KK);
        int c  = r / KK;
        int k  = r % KK;
        wt[(k * CIN + c) * COUT + co] = w[i];
    }
}

// ---- x [N][C][SP] -> xT [N][SP][C] (channel-last), LDS-tiled, coalesced both sides
__global__ __launch_bounds__(256) void transpose_x_kernel(const float* __restrict__ x,
                                                          float* __restrict__ xT) {
    __shared__ float sm[CIN][65];
    const int b   = blockIdx.x;          // 784 blocks, 64 positions each
    const int s0  = b * 64;
    const int n   = s0 / SP;
    const int sp0 = s0 % SP;
    const int t   = threadIdx.x;
#pragma unroll
    for (int it = 0; it < 8; ++it) {     // 2048 elements
        const int idx = it * 256 + t;
        const int c = idx >> 6, l = idx & 63;
        sm[c][l] = x[((size_t)n * CIN + c) * SP + sp0 + l];
    }
    __syncthreads();
#pragma unroll
    for (int it = 0; it < 8; ++it) {
        const int idx = it * 256 + t;
        const int l = idx >> 5, c = idx & 31;
        xT[((size_t)n * SP + sp0 + l) * CIN + c] = sm[c][l];
    }
}

template <bool CHLAST>
__global__ __launch_bounds__(256, 3) void dconv3d_kernel(const float* __restrict__ x,
                                                         const float* __restrict__ off,
                                                         const float* __restrict__ wt,
                                                         const float* __restrict__ bias,
                                                         float* __restrict__ out) {
    __shared__ float vt[2][CIN * VSTR];  // double-buffered interp tile, 16.9 KB

    // XCD-aware swizzle: each XCD gets a contiguous run of 98 blocks (bijective on 784)
    const int sb = (blockIdx.x & 7) * 98 + (blockIdx.x >> 3);
    const int s0 = sb * POSB;            // block never crosses batch (392*64 == SP)
    const int n  = s0 / SP;

    // interp persona: 4 threads per position, 8 channels each
    const int ipos = threadIdx.x >> 2;   // 0..63
    const int cg   = threadIdx.x & 3;    // channel group
    // gemm persona: lane = position, wave = Cout chunk (wave-uniform -> scalar weights)
    const int glane = threadIdx.x & 63;
    const int co0   = __builtin_amdgcn_readfirstlane((threadIdx.x >> 6) * CHUNK);

    const int sp = (s0 % SP) + ipos;
    const int to = sp / (HH * WW);
    const int hw = sp % (HH * WW);
    const int ho = hw / WW;
    const int wo = hw % WW;

    float acc[CHUNK];
#pragma unroll
    for (int i = 0; i < CHUNK; ++i) acc[i] = 0.f;

    const float* xn   = x + (size_t)n * CIN * SP;                 // [C][SP] layout
    const float* xTn  = x + ((size_t)n * SP + 0) * CIN;           // [SP][C] layout (same ptr arg, reinterpreted)
    const float* offn = off + (size_t)n * (3 * KK) * SP + sp;

    float o0 = offn[0];
    float o1 = offn[SP];
    float o2 = offn[2 * SP];

    for (int k = 0; k < KK; ++k) {
        const int kt  = k / 9;
        const int khh = (k / 3) % 3;
        const int kww = k % 3;

        const float pt = (float)(to - 1 + kt)  + o0;
        const float ph = (float)(ho - 1 + khh) + o1;
        const float pw = (float)(wo - 1 + kww) + o2;

        if (k + 1 < KK) {                 // prefetch next tap's offsets
            o0 = offn[((k + 1) * 3 + 0) * SP];
            o1 = offn[((k + 1) * 3 + 1) * SP];
            o2 = offn[((k + 1) * 3 + 2) * SP];
        }

        const float ft = floorf(pt), fh = floorf(ph), fw = floorf(pw);
        const float lt = pt - ft, lh = ph - fh, lw = pw - fw;
        const int t0 = (int)ft, h0 = (int)fh, w0 = (int)fw;

        float awt[2], awh[2], aww[2];
        int   it2[2], ih2[2], iw2[2];
        {
            const int t1 = t0 + 1;
            awt[0] = (t0 >= 0 && t0 < TT) ? (1.f - lt) : 0.f;
            awt[1] = (t1 >= 0 && t1 < TT) ? lt : 0.f;
            it2[0] = min(max(t0, 0), TT - 1);
            it2[1] = min(max(t1, 0), TT - 1);
        }
        {
            const int h1 = h0 + 1;
            awh[0] = (h0 >= 0 && h0 < HH) ? (1.f - lh) : 0.f;
            awh[1] = (h1 >= 0 && h1 < HH) ? lh : 0.f;
            ih2[0] = min(max(h0, 0), HH - 1);
            ih2[1] = min(max(h1, 0), HH - 1);
        }
        {
            const int w1 = w0 + 1;
            aww[0] = (w0 >= 0 && w0 < WW) ? (1.f - lw) : 0.f;
            aww[1] = (w1 >= 0 && w1 < WW) ? lw : 0.f;
            iw2[0] = min(max(w0, 0), WW - 1);
            iw2[1] = min(max(w1, 0), WW - 1);
        }

        int   a[8];
        float cw[8];
#pragma unroll
        for (int ci = 0; ci < 8; ++ci) {
            const int i0 = ci >> 2, i1 = (ci >> 1) & 1, i2 = ci & 1;
            a[ci]  = (it2[i0] * HH + ih2[i1]) * WW + iw2[i2];
            cw[ci] = awt[i0] * awh[i1] * aww[i2];
        }

        // ---- interp: this thread produces channels cg*8..cg*8+7 for position ipos
        float vacc[8];
#pragma unroll
        for (int j = 0; j < 8; ++j) vacc[j] = 0.f;

        if (CHLAST) {
#pragma unroll
            for (int ci = 0; ci < 8; ++ci) {
                const float4* p = (const float4*)(xTn + (size_t)a[ci] * CIN + cg * 8);
                const float4 u0 = p[0];
                const float4 u1 = p[1];
                const float  cwc = cw[ci];
                vacc[0] = fmaf(cwc, u0.x, vacc[0]);
                vacc[1] = fmaf(cwc, u0.y, vacc[1]);
                vacc[2] = fmaf(cwc, u0.z, vacc[2]);
                vacc[3] = fmaf(cwc, u0.w, vacc[3]);
                vacc[4] = fmaf(cwc, u1.x, vacc[4]);
                vacc[5] = fmaf(cwc, u1.y, vacc[5]);
                vacc[6] = fmaf(cwc, u1.z, vacc[6]);
                vacc[7] = fmaf(cwc, u1.w, vacc[7]);
            }
        } else {
#pragma unroll
            for (int j = 0; j < 8; ++j) {
                const float* xc = xn + (size_t)(cg * 8 + j) * SP;
#pragma unroll
                for (int ci = 0; ci < 8; ++ci) vacc[j] = fmaf(cw[ci], xc[a[ci]], vacc[j]);
            }
        }

        float* dst = &vt[k & 1][0];
#pragma unroll
        for (int j = 0; j < 8; ++j) dst[(cg * 8 + j) * VSTR + ipos] = vacc[j];

        __syncthreads();  // interp(k) visible; gemm(k-1) already done in program order

        // ---- GEMM: 16 Couts per thread, wave-uniform scalar weights
        const float* src = &vt[k & 1][0];
        const float* wk  = wt + (size_t)k * CIN * COUT + co0;
#pragma unroll
        for (int c = 0; c < CIN; ++c) {
            const float v = src[c * VSTR + glane];
            const float* wkc = wk + c * COUT;
#pragma unroll
            for (int i = 0; i < CHUNK; ++i) acc[i] = fmaf(v, wkc[i], acc[i]);
        }
    }

    const int spg = (s0 % SP) + glane;
    float* on = out + (size_t)n * COUT * SP + (size_t)co0 * SP + spg;
#pragma unroll
    for (int i = 0; i < CHUNK; ++i) on[i * SP] = acc[i] + bias[co0 + i];
}

extern "C" void kernel_launch(void* const* d_in, const int* in_sizes, int n_in,
                              void* d_out, int out_size, void* d_ws, size_t ws_size,
                              hipStream_t stream) {
    const float* x    = (const float*)d_in[0];
    const float* off  = (const float*)d_in[1];
    const float* w    = (const float*)d_in[2];
    const float* bias = (const float*)d_in[3];
    float* out        = (float*)d_out;

    const int blocks = (NB * SP) / POSB;  // 784

    const size_t xT_bytes = (size_t)NB * SP * CIN * sizeof(float);       // 6.42 MB
    const size_t wt_bytes = (size_t)COUT * CIN * KK * sizeof(float);     // 221 KB

    if (ws_size >= xT_bytes + wt_bytes) {
        float* xT  = (float*)d_ws;
        float* wtp = (float*)((char*)d_ws + xT_bytes);
        transpose_x_kernel<<<blocks, 256, 0, stream>>>(x, xT);
        transpose_w_kernel<<<(COUT * CIN * KK + 255) / 256, 256, 0, stream>>>(w, wtp);
        dconv3d_kernel<true><<<blocks, 256, 0, stream>>>(xT, off, wtp, bias, out);
    } else if (ws_size >= wt_bytes) {
        float* wtp = (float*)d_ws;
        transpose_w_kernel<<<(COUT * CIN * KK + 255) / 256, 256, 0, stream>>>(w, wtp);
        dconv3d_kernel<false><<<blocks, 256, 0, stream>>>(x, off, wtp, bias, out);
    }
}

// Round 5
// 165.723 us; speedup vs baseline: 12.0664x; 1.1544x over previous
//
#include <hip/hip_runtime.h>
#include <hip/hip_fp16.h>

#define CIN   32
#define COUT  64
#define TT    8
#define HH    56
#define WW    56
#define KK    27
#define SP    (TT * HH * WW)   // 25088
#define NB    2
#define NBLK  784              // (NB*SP)/64, 64 positions per block

typedef __attribute__((ext_vector_type(8)))  _Float16 half8;
typedef __attribute__((ext_vector_type(16))) float    f32x16;

// prep (fused): blocks [0,784): x [N][C][SP] fp32 -> xTh [N][SP][C] fp16 (channel-last)
//               blocks [784,811): weight [Cout][Cin][K] -> fp16 MFMA A-fragments
//               wf[k][ct][m][lane][j]: A[co = ct*32 + (lane&31)][c = m*16 + (lane>>5)*8 + j]
__global__ __launch_bounds__(256) void prep_kernel(const float* __restrict__ x,
                                                   const float* __restrict__ w,
                                                   __half* __restrict__ xTh,
                                                   __half* __restrict__ wf) {
    const int b = blockIdx.x;
    const int t = threadIdx.x;
    if (b < NBLK) {
        __shared__ float sm[CIN][65];
        const int s0 = b * 64, n = s0 / SP, sp0 = s0 % SP;
#pragma unroll
        for (int it = 0; it < 8; ++it) {
            const int idx = it * 256 + t, c = idx >> 6, l = idx & 63;
            sm[c][l] = x[((size_t)n * CIN + c) * SP + sp0 + l];
        }
        __syncthreads();
#pragma unroll
        for (int it = 0; it < 4; ++it) {   // 1024 half2 per block, coalesced
            const int idx = it * 256 + t, l = idx >> 4, cp = idx & 15;
            ((__half2*)xTh)[((size_t)n * SP + sp0 + l) * (CIN / 2) + cp] =
                __floats2half2_rn(sm[2 * cp][l], sm[2 * cp + 1][l]);
        }
    } else {
        const int k = b - NBLK;            // one tap per block, 2048 elements
#pragma unroll
        for (int it = 0; it < 8; ++it) {
            const int idx  = it * 256 + t; // [ct(2)][m(2)][lane(64)][j(8)]
            const int j    = idx & 7;
            const int lane = (idx >> 3) & 63;
            const int m    = (idx >> 9) & 1;
            const int ct   = (idx >> 10) & 1;
            const int co   = ct * 32 + (lane & 31);
            const int c    = m * 16 + (lane >> 5) * 8 + j;
            wf[((((size_t)k * 2 + ct) * 2 + m) * 64 + lane) * 8 + j] =
                __float2half(w[((size_t)co * CIN + c) * KK + k]);
        }
    }
}

__global__ __launch_bounds__(256, 4) void dconv3d_kernel(const __half* __restrict__ xTh,
                                                         const float* __restrict__ off,
                                                         const __half* __restrict__ wf,
                                                         const float* __restrict__ bias,
                                                         float* __restrict__ out) {
    // Double-buffered interpolated tile in B-fragment order:
    // vtB[buf][pos_tile][mfma_m][fraglane][8 fp16]   (8 KB total)
    __shared__ __half vtB[2][2][2][64][8];

    const int lane = threadIdx.x & 63;
    const int wv   = threadIdx.x >> 6;
    // interp persona: lane = position (0..63), wave = channel group (8 ch each)
    const int cg   = wv;
    // gemm persona: wave owns C-tile (co_tile ct, pos_tile pt)
    const int ct   = __builtin_amdgcn_readfirstlane(wv & 1);
    const int pt   = __builtin_amdgcn_readfirstlane(wv >> 1);

    // XCD-aware swizzle: contiguous sp range per XCD (bijective on 784; 392*64==SP)
    const int sb  = (blockIdx.x & 7) * 98 + (blockIdx.x >> 3);
    const int s0  = sb * 64;
    const int n   = s0 / SP;
    const int spb = s0 % SP;

    const int sp = spb + lane;
    const int to = sp / (HH * WW);
    const int hw = sp % (HH * WW);
    const int ho = hw / WW;
    const int wo = hw % WW;

    f32x16 acc;
#pragma unroll
    for (int i = 0; i < 16; ++i) acc[i] = 0.f;

    const __half* xn   = xTh + (size_t)n * SP * CIN;          // [SP][C] fp16
    const float*  offn = off + (size_t)n * (3 * KK) * SP + sp;

    float o0 = offn[0];
    float o1 = offn[SP];
    float o2 = offn[2 * SP];

    for (int k = 0; k < KK; ++k) {
        const int kt  = k / 9;
        const int khh = (k / 3) % 3;
        const int kww = k % 3;

        const float pt_ = (float)(to - 1 + kt)  + o0;
        const float ph_ = (float)(ho - 1 + khh) + o1;
        const float pw_ = (float)(wo - 1 + kww) + o2;

        if (k + 1 < KK) {                  // prefetch next tap's offsets
            o0 = offn[((k + 1) * 3 + 0) * SP];
            o1 = offn[((k + 1) * 3 + 1) * SP];
            o2 = offn[((k + 1) * 3 + 2) * SP];
        }

        const float ft = floorf(pt_), fh = floorf(ph_), fw = floorf(pw_);
        const float lt = pt_ - ft, lh = ph_ - fh, lw = pw_ - fw;
        const int t0 = (int)ft, h0 = (int)fh, w0 = (int)fw;

        float awt[2], awh[2], aww[2];
        int   it2[2], ih2[2], iw2[2];
        {
            const int t1 = t0 + 1;
            awt[0] = (t0 >= 0 && t0 < TT) ? (1.f - lt) : 0.f;
            awt[1] = (t1 >= 0 && t1 < TT) ? lt : 0.f;
            it2[0] = min(max(t0, 0), TT - 1);
            it2[1] = min(max(t1, 0), TT - 1);
        }
        {
            const int h1 = h0 + 1;
            awh[0] = (h0 >= 0 && h0 < HH) ? (1.f - lh) : 0.f;
            awh[1] = (h1 >= 0 && h1 < HH) ? lh : 0.f;
            ih2[0] = min(max(h0, 0), HH - 1);
            ih2[1] = min(max(h1, 0), HH - 1);
        }
        {
            const int w1 = w0 + 1;
            aww[0] = (w0 >= 0 && w0 < WW) ? (1.f - lw) : 0.f;
            aww[1] = (w1 >= 0 && w1 < WW) ? lw : 0.f;
            iw2[0] = min(max(w0, 0), WW - 1);
            iw2[1] = min(max(w1, 0), WW - 1);
        }

        int   a[8];
        float cw[8];
#pragma unroll
        for (int ci = 0; ci < 8; ++ci) {
            const int i0 = ci >> 2, i1 = (ci >> 1) & 1, i2 = ci & 1;
            a[ci]  = (it2[i0] * HH + ih2[i1]) * WW + iw2[i2];
            cw[ci] = awt[i0] * awh[i1] * aww[i2];
        }

        // ---- interp: 8 channels (cg*8..+7) for position `lane`, fp16 packed math
        __half2 vacc[4];
#pragma unroll
        for (int j = 0; j < 4; ++j) vacc[j] = __floats2half2_rn(0.f, 0.f);

#pragma unroll
        for (int ci = 0; ci < 8; ++ci) {
            const float4 u = *(const float4*)(xn + (size_t)a[ci] * CIN + cg * 8); // 8 fp16
            const __half2* uh = (const __half2*)&u;
            const __half2 cw2 = __float2half2_rn(cw[ci]);
            vacc[0] = __hfma2(cw2, uh[0], vacc[0]);
            vacc[1] = __hfma2(cw2, uh[1], vacc[1]);
            vacc[2] = __hfma2(cw2, uh[2], vacc[2]);
            vacc[3] = __hfma2(cw2, uh[3], vacc[3]);
        }

        // write directly in B-fragment order: one b128, contiguous per wave
        *(float4*)&vtB[k & 1][lane >> 5][cg >> 1][(cg & 1) * 32 + (lane & 31)][0] =
            *(const float4*)vacc;

        __syncthreads();  // interp(k) visible; dbuf makes one barrier/tap sufficient

        // ---- GEMM: wave's 32x32 C-tile, K=32 as 2 MFMAs
        const half8 b0 = *(const half8*)&vtB[k & 1][pt][0][lane][0];
        const half8 b1 = *(const half8*)&vtB[k & 1][pt][1][lane][0];
        const half8 a0 = *(const half8*)(wf + ((((size_t)k * 2 + ct) * 2 + 0) * 64 + lane) * 8);
        const half8 a1 = *(const half8*)(wf + ((((size_t)k * 2 + ct) * 2 + 1) * 64 + lane) * 8);
        acc = __builtin_amdgcn_mfma_f32_32x32x16_f16(a0, b0, acc, 0, 0, 0);
        acc = __builtin_amdgcn_mfma_f32_32x32x16_f16(a1, b1, acc, 0, 0, 0);
    }

    // epilogue: HW-verified C/D map: col=lane&31, row=(reg&3)+8*(reg>>2)+4*(lane>>5)
#pragma unroll
    for (int r = 0; r < 16; ++r) {
        const int row = (r & 3) + 8 * (r >> 2) + 4 * (lane >> 5);
        const int co  = ct * 32 + row;
        const int pos = pt * 32 + (lane & 31);
        out[((size_t)n * COUT + co) * SP + spb + pos] = acc[r] + bias[co];
    }
}

extern "C" void kernel_launch(void* const* d_in, const int* in_sizes, int n_in,
                              void* d_out, int out_size, void* d_ws, size_t ws_size,
                              hipStream_t stream) {
    const float* x    = (const float*)d_in[0];
    const float* off  = (const float*)d_in[1];
    const float* w    = (const float*)d_in[2];
    const float* bias = (const float*)d_in[3];
    float* out        = (float*)d_out;

    // ws: [0, 128KB) = weight A-frags (110,592 B), [128KB, ...) = xTh fp16 (3,211,264 B)
    __half* wf  = (__half*)d_ws;
    __half* xTh = (__half*)((char*)d_ws + (128 << 10));

    prep_kernel<<<NBLK + KK, 256, 0, stream>>>(x, w, xTh, wf);
    dconv3d_kernel<<<NBLK, 256, 0, stream>>>(xTh, off, wf, bias, out);
}